// Round 5
// baseline (1106.376 us; speedup 1.0000x reference)
//
#include <hip/hip_runtime.h>
#include <cstdint>
#include <cstddef>

#define WAYS  100
#define SHOTS 5
#define NQ    10000
#define DIM   2048
#define KSEL  512

#define BQ 64
#define BW 64
#define BK 32
#define PAD 4
#define CQ 64

struct Ctrl {
  double klsum[2];   // [0]=dctl, [1]=resl
  double wsum[2];
  float  w0[2];
  int    R, Dn;
  unsigned int T[8];
  int rem[8];
  int kk[8];
};

__device__ __forceinline__ unsigned int monokey(float f){
  unsigned int b = __float_as_uint(f);
  return (b & 0x80000000u) ? ~b : (b | 0x80000000u);
}
__device__ __forceinline__ float dekey(unsigned int k){
  return (k & 0x80000000u) ? __uint_as_float(k & 0x7FFFFFFFu)
                           : __uint_as_float(~k);
}
__device__ __forceinline__ int decn(int sel, const Ctrl* c){
  return sel == 0 ? NQ : (sel == 1 ? c->R : c->Dn);
}

// ---- prototypes: mean over shots, then row l2-norm -------------------------
__global__ void proto_kernel(const float* __restrict__ xs, const float* __restrict__ dsh,
                             float* __restrict__ protoX, float* __restrict__ protoD){
  int b = blockIdx.x;
  const float* src = (b < WAYS) ? xs : dsh;
  float* dst = (b < WAYS) ? protoX : protoD;
  int w = (b < WAYS) ? b : b - WAYS;
  __shared__ float meanv[DIM];
  __shared__ float red[256];
  float loc = 0.f;
  for (int d = threadIdx.x; d < DIM; d += 256){
    float s = 0.f;
    for (int sh = 0; sh < SHOTS; sh++) s += src[((size_t)w*SHOTS + sh)*DIM + d];
    float m = s / (float)SHOTS;
    meanv[d] = m;
    loc += m*m;
  }
  red[threadIdx.x] = loc; __syncthreads();
  for (int st = 128; st > 0; st >>= 1){
    if (threadIdx.x < st) red[threadIdx.x] += red[threadIdx.x + st];
    __syncthreads();
  }
  float inv = 1.0f / fmaxf(sqrtf(red[0]), 1e-12f);
  for (int d = threadIdx.x; d < DIM; d += 256)
    dst[(size_t)w*DIM + d] = meanv[d] * inv;
}

// ---- per-query inverse L2 norm (4 rows / 256-thread block) -----------------
__global__ __launch_bounds__(256)
void invnorm_kernel(const float* __restrict__ xq, const float* __restrict__ dq,
                    float* __restrict__ invnX, float* __restrict__ invnD){
  int row = blockIdx.x * 4 + (threadIdx.x >> 6);
  if (row >= 2*NQ) return;
  int lane = threadIdx.x & 63;
  const float* src = (row < NQ) ? xq : dq;
  float* dst = (row < NQ) ? invnX : invnD;
  int q = (row < NQ) ? row : row - NQ;
  const float4* r4 = (const float4*)(src + (size_t)q*DIM);
  float s = 0.f;
  for (int i = lane; i < DIM/4; i += 64){
    float4 v = r4[i];
    s += v.x*v.x + v.y*v.y + v.z*v.z + v.w*v.w;
  }
  for (int off = 32; off > 0; off >>= 1) s += __shfl_down(s, off);
  if (lane == 0) dst[q] = 1.0f / fmaxf(sqrtf(s), 1e-12f);
}

// ---- batched split-K GEMM (64x64 tile, 4x4/thread, register prefetch) ------
struct GemmArgs {
  const float* feat[4];
  const float* proto[4];
  const int*   idx[4];
  float*       outP[4];      // + s*NQ*WAYS + rowOff*WAYS
  const float* invn[4];
  int          nSel[4];      // 0->NQ, 1->R, 2->Dn
  int          offSel[4];    // 1 -> row offset ctrl->R in output
  int          splitk;
  int          applyInvn;
  const Ctrl*  ctrl;
};

__global__ __launch_bounds__(256)
void gemm_batched(GemmArgs ga){
  int batch = blockIdx.z / ga.splitk;
  int s     = blockIdx.z % ga.splitk;
  int n = decn(ga.nSel[batch], ga.ctrl);
  int qBase = blockIdx.x * BQ;
  if (qBase >= n) return;
  int wBase = blockIdx.y * BW;
  int kLen  = DIM / ga.splitk;
  int kStart = s * kLen;

  __shared__ float As[BK][BQ+PAD];
  __shared__ float Bs[BK][BW+PAD];

  const float* feat  = ga.feat[batch];
  const float* proto = ga.proto[batch];
  const int*   idxl  = ga.idx[batch];

  int t = threadIdx.x;
  int lr = t & 63;          // staging row within tile
  int kv = t >> 6;          // 0..3 -> k-chunks kv*4 and kv*4+16
  int arow = qBase + lr;
  int garow = idxl ? idxl[min(arow, n-1)] : min(arow, n-1);
  const float* pA = feat + (size_t)garow*DIM + kStart + kv*4;
  int wrow = wBase + lr;
  bool bok = (wrow < WAYS);
  const float* pB = proto + (size_t)wrow*DIM + kStart + kv*4;

  int tx = t & 15, ty = t >> 4;      // w: tx*4, q: ty*4
  float acc[4][4];
#pragma unroll
  for (int i = 0; i < 4; i++)
#pragma unroll
    for (int j = 0; j < 4; j++) acc[i][j] = 0.f;

  float4 av0, av1, bv0, bv1;
  const float4 z4 = make_float4(0.f,0.f,0.f,0.f);
  av0 = *(const float4*)pA;
  av1 = *(const float4*)(pA + 16);
  bv0 = bok ? *(const float4*)pB : z4;
  bv1 = bok ? *(const float4*)(pB + 16) : z4;

  for (int k0 = 0; k0 < kLen; k0 += BK){
    __syncthreads();
    int kk = kv*4;
    As[kk+0 ][lr]=av0.x; As[kk+1 ][lr]=av0.y; As[kk+2 ][lr]=av0.z; As[kk+3 ][lr]=av0.w;
    As[kk+16][lr]=av1.x; As[kk+17][lr]=av1.y; As[kk+18][lr]=av1.z; As[kk+19][lr]=av1.w;
    Bs[kk+0 ][lr]=bv0.x; Bs[kk+1 ][lr]=bv0.y; Bs[kk+2 ][lr]=bv0.z; Bs[kk+3 ][lr]=bv0.w;
    Bs[kk+16][lr]=bv1.x; Bs[kk+17][lr]=bv1.y; Bs[kk+18][lr]=bv1.z; Bs[kk+19][lr]=bv1.w;
    __syncthreads();
    if (k0 + BK < kLen){     // prefetch next tile into registers
      const float* qA = pA + k0 + BK;
      const float* qB = pB + k0 + BK;
      av0 = *(const float4*)qA; av1 = *(const float4*)(qA + 16);
      bv0 = bok ? *(const float4*)qB : z4;
      bv1 = bok ? *(const float4*)(qB + 16) : z4;
    }
#pragma unroll
    for (int kk2 = 0; kk2 < BK; kk2++){
      float4 a = *(const float4*)&As[kk2][ty*4];
      float4 b = *(const float4*)&Bs[kk2][tx*4];
      acc[0][0]+=a.x*b.x; acc[0][1]+=a.x*b.y; acc[0][2]+=a.x*b.z; acc[0][3]+=a.x*b.w;
      acc[1][0]+=a.y*b.x; acc[1][1]+=a.y*b.y; acc[1][2]+=a.y*b.z; acc[1][3]+=a.y*b.w;
      acc[2][0]+=a.z*b.x; acc[2][1]+=a.z*b.y; acc[2][2]+=a.z*b.z; acc[2][3]+=a.z*b.w;
      acc[3][0]+=a.w*b.x; acc[3][1]+=a.w*b.y; acc[3][2]+=a.w*b.z; acc[3][3]+=a.w*b.w;
    }
  }
  int rowOff = ga.offSel[batch] ? ga.ctrl->R : 0;
  float* outBase = ga.outP[batch] + ((size_t)s*NQ + (size_t)rowOff)*WAYS;
  int wc = wBase + tx*4;
#pragma unroll
  for (int i = 0; i < 4; i++){
    int q = qBase + ty*4 + i;
    if (q >= n) continue;
    float scr = 1.f;
    if (ga.applyInvn){
      int gq = idxl ? idxl[q] : q;
      scr = ga.invn[batch][gq];
    }
    float* dst = outBase + (size_t)q*WAYS + wc;
    if (wc + 3 < WAYS){
      *(float4*)dst = make_float4(acc[i][0]*scr, acc[i][1]*scr, acc[i][2]*scr, acc[i][3]*scr);
    } else {
#pragma unroll
      for (int j = 0; j < 4; j++) if (wc + j < WAYS) dst[j] = acc[i][j]*scr;
    }
  }
}

// ---- combine K-slices (fixed order), apply invn, colSq; in-place safe ------
struct CombArgs {
  const float* P;            // + b*splitk*NQ*WAYS
  const float* invn[2];
  float* Ltgt[2];            // may alias P slice 0
  double* colSq;             // + b*WAYS
  int splitk;
};
__global__ __launch_bounds__(256)
void combine_batched(CombArgs ca){
  int b = blockIdx.y;
  int qBase = blockIdx.x * CQ;
  int t = threadIdx.x;
  int j = t % 25, r = t / 25;
  const float* Pb = ca.P + (size_t)b*ca.splitk*NQ*WAYS;
  const float* invn = ca.invn[b];
  float* L = ca.Ltgt[b];
  double sq0=0.0, sq1=0.0, sq2=0.0, sq3=0.0;
  if (r < 10){
    for (int i = r; i < CQ; i += 10){
      int q = qBase + i;
      if (q >= NQ) break;
      float sc = invn[q];
      const float* p0 = Pb + (size_t)q*WAYS + 4*j;
      float4 v = *(const float4*)p0;
      for (int s2 = 1; s2 < ca.splitk; s2++){
        float4 u = *(const float4*)(p0 + (size_t)s2*NQ*WAYS);
        v.x += u.x; v.y += u.y; v.z += u.z; v.w += u.w;
      }
      v.x *= sc; v.y *= sc; v.z *= sc; v.w *= sc;
      *(float4*)(L + (size_t)q*WAYS + 4*j) = v;
      sq0 += (double)v.x*(double)v.x;
      sq1 += (double)v.y*(double)v.y;
      sq2 += (double)v.z*(double)v.z;
      sq3 += (double)v.w*(double)v.w;
    }
  }
  __shared__ double red[WAYS][10];
  if (r < 10){
    red[4*j+0][r]=sq0; red[4*j+1][r]=sq1; red[4*j+2][r]=sq2; red[4*j+3][r]=sq3;
  }
  __syncthreads();
  if (t < WAYS){
    double s2 = 0.0;
#pragma unroll
    for (int rr = 0; rr < 10; rr++) s2 += red[t][rr];
    atomicAdd(ca.colSq + (size_t)b*WAYS + t, s2);
  }
}

// ---- column stats: colSq + optional per-way min/max (packed-row aware) -----
struct StatArgs {
  const float* Lsrc[4];
  const int*   idx[4];
  int nSel[4];
  int offSel[4];
  double* colSq;          // + b*WAYS
  unsigned* maxK;         // null -> skip minmax
  unsigned* negK;
  const Ctrl* ctrl;
};
__global__ __launch_bounds__(256)
void stats_batched(StatArgs sa){
  int b = blockIdx.y;
  int n = decn(sa.nSel[b], sa.ctrl);
  int qBase = blockIdx.x * CQ;
  if (qBase >= n) return;
  int t = threadIdx.x;
  int j = t % 25, r = t / 25;
  double sq0=0.0, sq1=0.0, sq2=0.0, sq3=0.0;
  float mx0=-3.4e38f,mx1=-3.4e38f,mx2=-3.4e38f,mx3=-3.4e38f;
  float mn0= 3.4e38f,mn1= 3.4e38f,mn2= 3.4e38f,mn3= 3.4e38f;
  if (r < 10){
    const int* idx = sa.idx[b];
    int rowOff = sa.offSel[b] ? sa.ctrl->R : 0;
    const float* L = sa.Lsrc[b] + (size_t)rowOff*WAYS;
    for (int i = r; i < CQ; i += 10){
      int q = qBase + i;
      if (q >= n) break;
      int gq = idx ? idx[q] : q;
      float4 v = *(const float4*)(L + (size_t)gq*WAYS + 4*j);
      sq0 += (double)v.x*(double)v.x; sq1 += (double)v.y*(double)v.y;
      sq2 += (double)v.z*(double)v.z; sq3 += (double)v.w*(double)v.w;
      mx0=fmaxf(mx0,v.x); mx1=fmaxf(mx1,v.y); mx2=fmaxf(mx2,v.z); mx3=fmaxf(mx3,v.w);
      mn0=fminf(mn0,v.x); mn1=fminf(mn1,v.y); mn2=fminf(mn2,v.z); mn3=fminf(mn3,v.w);
    }
  }
  __shared__ double red[WAYS][10];
  if (r < 10){
    red[4*j+0][r]=sq0; red[4*j+1][r]=sq1; red[4*j+2][r]=sq2; red[4*j+3][r]=sq3;
  }
  __syncthreads();
  if (t < WAYS){
    double s2 = 0.0;
#pragma unroll
    for (int rr = 0; rr < 10; rr++) s2 += red[t][rr];
    atomicAdd(sa.colSq + (size_t)b*WAYS + t, s2);
  }
  if (sa.maxK){
    __shared__ float redMx[WAYS][10], redMn[WAYS][10];
    if (r < 10){
      redMx[4*j+0][r]=mx0; redMx[4*j+1][r]=mx1; redMx[4*j+2][r]=mx2; redMx[4*j+3][r]=mx3;
      redMn[4*j+0][r]=mn0; redMn[4*j+1][r]=mn1; redMn[4*j+2][r]=mn2; redMn[4*j+3][r]=mn3;
    }
    __syncthreads();
    if (t < WAYS){
      float mx = -3.4e38f, mn = 3.4e38f;
#pragma unroll
      for (int rr = 0; rr < 10; rr++){ mx = fmaxf(mx, redMx[t][rr]); mn = fminf(mn, redMn[t][rr]); }
      atomicMax(sa.maxK + (size_t)b*WAYS + t, monokey(mx));
      atomicMax(sa.negK + (size_t)b*WAYS + t, monokey(-mn));
    }
  }
}

// ---- per-row max/argmax with lazy scale ------------------------------------
struct RS1Args {
  const float* Lsrc[4];
  const int*   idx[4];
  int nSel[4];
  const double* colSq;   // + b*WAYS
  const float* tpP;
  const Ctrl* ctrl;
  float* absCert; unsigned* keys; int* pseudo;   // + b*NQ
};
__global__ __launch_bounds__(256)
void rowstats1_b(RS1Args a){
  int b = blockIdx.y;
  int n = decn(a.nSel[b], a.ctrl);
  __shared__ float sc[WAYS];
  int t = threadIdx.x;
  if (t < WAYS) sc[t] = (*a.tpP) / ((float)sqrt(a.colSq[(size_t)b*WAYS+t]) + 1e-6f);
  __syncthreads();
  int q = blockIdx.x*256 + t;
  if (q >= n) return;
  int gq = a.idx[b] ? a.idx[b][q] : q;
  const float* row = a.Lsrc[b] + (size_t)gq*WAYS;
  float m = row[0]*sc[0]; int am = 0;
  for (int w = 1; w < WAYS; w++){
    float v = row[w]*sc[w];
    if (v > m){ m = v; am = w; }
  }
  a.absCert[(size_t)b*NQ+q] = m;
  a.pseudo [(size_t)b*NQ+q] = am;
  a.keys   [(size_t)b*NQ+q] = monokey(m);
}

// ---- per-row max + negative entropy (full, batched) ------------------------
struct RS2Args {
  const float* Lsrc[2];
  const double* colSq;   // + b*WAYS
  const float* tpP;
  float* absC; float* relC;   // + b*NQ
};
__global__ __launch_bounds__(256)
void rowstats2_b(RS2Args a){
  int b = blockIdx.y;
  __shared__ float sc[WAYS];
  int t = threadIdx.x;
  if (t < WAYS) sc[t] = (*a.tpP) / ((float)sqrt(a.colSq[(size_t)b*WAYS+t]) + 1e-6f);
  __syncthreads();
  int q = blockIdx.x*256 + t;
  if (q >= NQ) return;
  const float* row = a.Lsrc[b] + (size_t)q*WAYS;
  float m = row[0]*sc[0];
  for (int w = 1; w < WAYS; w++) m = fmaxf(m, row[w]*sc[w]);
  float s = 0.f;
  for (int w = 0; w < WAYS; w++) s += expf(row[w]*sc[w] - m);
  float inv = 1.0f / s, rel = 0.f;
  for (int w = 0; w < WAYS; w++){
    float p = expf(row[w]*sc[w] - m) * inv;
    rel += p * logf(p + 1e-10f);
  }
  a.absC[(size_t)b*NQ+q] = m;
  a.relC[(size_t)b*NQ+q] = rel;
}

// ---- fused radix-select + deterministic stable gather (batched) ------------
struct SGArgs {
  const unsigned* keys; const float* absCert;   // + b*NQ
  int nSel[4]; int instBase;
  int* selIdx; float* selVal;                    // + b*KSEL
  Ctrl* ctrl;
};
__global__ __launch_bounds__(1024)
void selectgather_b(SGArgs a){
  int b = blockIdx.x;
  int inst = a.instBase + b;
  int n = decn(a.nSel[b], a.ctrl);
  int k = n < KSEL ? n : KSEL;
  const unsigned* keys = a.keys + (size_t)b*NQ;
  const float* absCert = a.absCert + (size_t)b*NQ;
  int* selIdx = a.selIdx + b*KSEL;
  float* selVal = a.selVal + b*KSEL;
  __shared__ int hist[256];
  __shared__ unsigned sprefix;
  __shared__ int srem;
  int t = threadIdx.x;
  if (t == 0){ sprefix = 0u; srem = k; }
  __syncthreads();
  int nv4 = n >> 2;
  for (int pass = 0; pass < 4; pass++){
    int shift = 24 - 8*pass;
    if (t < 256) hist[t] = 0;
    __syncthreads();
    unsigned pref = sprefix;
    unsigned mask = (pass == 0) ? 0u : (0xFFFFFFFFu << (shift + 8));
    for (int i = t; i < nv4; i += 1024){
      uint4 kv = ((const uint4*)keys)[i];
      if ((kv.x & mask) == pref) atomicAdd(&hist[(kv.x >> shift) & 255], 1);
      if ((kv.y & mask) == pref) atomicAdd(&hist[(kv.y >> shift) & 255], 1);
      if ((kv.z & mask) == pref) atomicAdd(&hist[(kv.z >> shift) & 255], 1);
      if ((kv.w & mask) == pref) atomicAdd(&hist[(kv.w >> shift) & 255], 1);
    }
    for (int i = 4*nv4 + t; i < n; i += 1024){
      unsigned key = keys[i];
      if ((key & mask) == pref) atomicAdd(&hist[(key >> shift) & 255], 1);
    }
    __syncthreads();
    if (t == 0){
      int acc = 0, rem = srem, sel = 0;
      for (int b2 = 255; b2 >= 0; b2--){
        int h = hist[b2];
        if (acc + h >= rem){ sel = b2; srem = rem - acc; break; }
        acc += h;
      }
      sprefix = pref | ((unsigned)sel << shift);
    }
    __syncthreads();
  }
  unsigned T = sprefix;
  int rem = srem;
  if (t == 0){ a.ctrl->T[inst] = T; a.ctrl->rem[inst] = rem; a.ctrl->kk[inst] = k; }
  int cntGT = k - rem;
  const int CH = 10;
  int q0 = t*CH;
  int fg[CH], fe[CH]; int cg = 0, ce = 0;
  for (int i = 0; i < CH; i++){
    int q = q0 + i; int g = 0, e = 0;
    if (q < n){ unsigned key = keys[q]; g = key > T; e = (key == T); }
    fg[i] = g; fe[i] = e; cg += g; ce += e;
  }
  __shared__ int sG[1024], sE[1024];
  sG[t] = cg; sE[t] = ce; __syncthreads();
  for (int s = 1; s < 1024; s <<= 1){
    int vg = t >= s ? sG[t-s] : 0;
    int ve = t >= s ? sE[t-s] : 0;
    __syncthreads();
    sG[t] += vg; sE[t] += ve;
    __syncthreads();
  }
  int posG = sG[t] - cg, posE = sE[t] - ce;
  for (int i = 0; i < CH; i++){
    int q = q0 + i;
    if (q >= n) break;
    if (fg[i]){ selIdx[posG] = q; selVal[posG] = absCert[q]; posG++; }
    else if (fe[i]){
      if (posE < rem){ selIdx[cntGT+posE] = q; selVal[cntGT+posE] = absCert[q]; }
      posE++;
    }
  }
}

// ---- deterministic proto refine (batched) ----------------------------------
struct RefArgs {
  const float* feat[4]; const int* idx[4];
  const float* invn[4]; const float* proto[4];
  const int* selIdx; const float* selVal;   // + b*KSEL
  const int* pseudo;                        // + b*NQ
  float* protoRef;                          // + b*WAYS*DIM
  int instBase;
  const Ctrl* ctrl;
};
__global__ __launch_bounds__(256)
void refine_b(RefArgs a){
  int b = blockIdx.y;
  int w = blockIdx.x;
  int k = a.ctrl->kk[a.instBase + b];
  const int* selIdx = a.selIdx + b*KSEL;
  const float* selVal = a.selVal + b*KSEL;
  const int* pseudo = a.pseudo + (size_t)b*NQ;
  const int* idxl = a.idx[b];
  __shared__ int   sRow[KSEL];
  __shared__ float sCoef[KSEL];
  int t = threadIdx.x;
  for (int j = t; j < k; j += 256){
    int srow = selIdx[j];
    int grow = idxl ? idxl[srow] : srow;
    sRow[j]  = (pseudo[srow] == w) ? grow : -1;
    sCoef[j] = selVal[j] * a.invn[b][grow] / (float)k;
  }
  __syncthreads();
  float4 acc0 = make_float4(0.f,0.f,0.f,0.f);
  float4 acc1 = make_float4(0.f,0.f,0.f,0.f);
  int d0 = t*4, d1 = t*4 + 1024;
  const float* feat = a.feat[b];
  for (int j = 0; j < k; j++){
    int grow = sRow[j];
    if (grow < 0) continue;
    float c = sCoef[j];
    const float* fr = feat + (size_t)grow*DIM;
    float4 f0 = *(const float4*)(fr + d0);
    float4 f1 = *(const float4*)(fr + d1);
    acc0.x += c*f0.x; acc0.y += c*f0.y; acc0.z += c*f0.z; acc0.w += c*f0.w;
    acc1.x += c*f1.x; acc1.y += c*f1.y; acc1.z += c*f1.z; acc1.w += c*f1.w;
  }
  const float* pw = a.proto[b] + (size_t)w*DIM;
  float* pr = a.protoRef + ((size_t)b*WAYS + w)*DIM;
  float4 p0 = *(const float4*)(pw + d0);
  float4 p1 = *(const float4*)(pw + d1);
  *(float4*)(pr + d0) = make_float4(p0.x+acc0.x, p0.y+acc0.y, p0.z+acc0.z, p0.w+acc0.w);
  *(float4*)(pr + d1) = make_float4(p1.x+acc1.x, p1.y+acc1.y, p1.z+acc1.z, p1.w+acc1.w);
}

// ---- diff sign partition + index + w_r/w_f outputs -------------------------
__global__ __launch_bounds__(1024)
void diff_partition(const float* __restrict__ absC, const float* __restrict__ relC,
                    Ctrl* ctrl, int* __restrict__ resIdx, int* __restrict__ dctIdx,
                    float* __restrict__ out){
  const float* absCx = absC;        const float* absCd = absC + NQ;
  const float* relCx = relC;        const float* relCd = relC + NQ;
  const int CH = 10;
  int t = threadIdx.x, q0 = t*CH;
  int fr[CH], fd[CH]; int cr = 0, cd = 0;
  for (int i = 0; i < CH; i++){
    int q = q0 + i; int r = 0, dn = 0;
    if (q < NQ){
      float dv = absCx[q] - absCd[q] + relCx[q] - relCd[q];
      r = dv > 0.f; dn = dv < 0.f;
    }
    fr[i] = r; fd[i] = dn; cr += r; cd += dn;
  }
  __shared__ int sR[1024], sD[1024];
  sR[t] = cr; sD[t] = cd; __syncthreads();
  for (int s = 1; s < 1024; s <<= 1){
    int vr = t >= s ? sR[t-s] : 0;
    int vd = t >= s ? sD[t-s] : 0;
    __syncthreads();
    sR[t] += vr; sD[t] += vd;
    __syncthreads();
  }
  int R = sR[1023], Dn = sD[1023];
  int posR = sR[t] - cr, posD = sD[t] - cd;
  if (t == 0){ ctrl->R = R; ctrl->Dn = Dn; }
  for (int i = 0; i < CH; i++){
    int q = q0 + i;
    if (q >= NQ) break;
    if (fr[i]){ resIdx[posR] = q; out[2+posR] = (float)q; posR++; }
    if (fd[i]){ dctIdx[posD] = q; out[2+R+posD] = (float)q; posD++; }
  }
  for (int q = t; q < NQ; q += 1024){
    float a = absCx[q], b = absCd[q];
    float den = fmaxf(a + b, 1e-8f);
    out[2+R+Dn+q]      = a / den;
    out[2+R+Dn+NQ+q]   = b / den;
  }
}

// ---- per-way sum of exp(v*sc - m) (row-major, batched, packed rows) --------
struct SEArgs {
  const float* Lsrc[4];
  int nSel[4];
  int offSel[4];
  const double* colSq;       // + b*WAYS
  const unsigned* maxK; const unsigned* negK;
  double* sumExp;            // + b*WAYS
  const float* tpP;
  const Ctrl* ctrl;
};
__global__ __launch_bounds__(256)
void sumexp_batched(SEArgs a){
  int b = blockIdx.y;
  int n = decn(a.nSel[b], a.ctrl);
  int t = threadIdx.x;
  __shared__ float sc[WAYS], mv[WAYS];
  if (t < WAYS){
    float s = (*a.tpP) / ((float)sqrt(a.colSq[(size_t)b*WAYS+t]) + 1e-6f);
    float mxv = dekey(a.maxK[(size_t)b*WAYS+t]);
    float mnv = -dekey(a.negK[(size_t)b*WAYS+t]);
    sc[t] = s; mv[t] = (s >= 0.f) ? s*mxv : s*mnv;
  }
  __syncthreads();
  int qBase = blockIdx.x * CQ;
  if (qBase >= n) return;
  int j = t % 25, r = t / 25;
  double e0=0.0,e1=0.0,e2=0.0,e3=0.0;
  if (r < 10){
    int rowOff = a.offSel[b] ? a.ctrl->R : 0;
    const float* L = a.Lsrc[b] + (size_t)rowOff*WAYS;
    float s0=sc[4*j+0], s1=sc[4*j+1], s2=sc[4*j+2], s3=sc[4*j+3];
    float m0=mv[4*j+0], m1=mv[4*j+1], m2=mv[4*j+2], m3=mv[4*j+3];
    for (int i = r; i < CQ; i += 10){
      int q = qBase + i;
      if (q >= n) break;
      float4 v = *(const float4*)(L + (size_t)q*WAYS + 4*j);
      e0 += (double)expf(v.x*s0 - m0);
      e1 += (double)expf(v.y*s1 - m1);
      e2 += (double)expf(v.z*s2 - m2);
      e3 += (double)expf(v.w*s3 - m3);
    }
  }
  __shared__ double red[WAYS][10];
  if (r < 10){
    red[4*j+0][r]=e0; red[4*j+1][r]=e1; red[4*j+2][r]=e2; red[4*j+3][r]=e3;
  }
  __syncthreads();
  if (t < WAYS){
    double s2 = 0.0;
#pragma unroll
    for (int rr = 0; rr < 10; rr++) s2 += red[t][rr];
    atomicAdd(a.sumExp + (size_t)b*WAYS + t, s2);
  }
}

// ---- KL sum (two pairs batched, packed rows) --------------------------------
struct KLArgs {
  const float* bufs[4];
  int offSel[4];
  const double* colSq2;      // + b*WAYS
  const unsigned* maxK; const unsigned* negK; const double* sumExp;
  const float* tpP;
  Ctrl* ctrl;
};
__global__ __launch_bounds__(256)
void klsum_batched(KLArgs a){
  int p = blockIdx.y;
  int bL = p ? 3 : 1, bH = p ? 2 : 0;
  int n = p ? a.ctrl->Dn : a.ctrl->R;
  __shared__ float scL[WAYS], lseL[WAYS], scH[WAYS], lseH[WAYS];
  int t = threadIdx.x;
  if (t < WAYS){
    float tp = *a.tpP;
    {
      float s = tp / ((float)sqrt(a.colSq2[(size_t)bL*WAYS+t]) + 1e-6f);
      float mxv = dekey(a.maxK[(size_t)bL*WAYS+t]);
      float mnv = -dekey(a.negK[(size_t)bL*WAYS+t]);
      float m = (s >= 0.f) ? s*mxv : s*mnv;
      scL[t] = s; lseL[t] = m + (float)log(a.sumExp[(size_t)bL*WAYS+t]);
    }
    {
      float s = tp / ((float)sqrt(a.colSq2[(size_t)bH*WAYS+t]) + 1e-6f);
      float mxv = dekey(a.maxK[(size_t)bH*WAYS+t]);
      float mnv = -dekey(a.negK[(size_t)bH*WAYS+t]);
      float m = (s >= 0.f) ? s*mxv : s*mnv;
      scH[t] = s; lseH[t] = m + (float)log(a.sumExp[(size_t)bH*WAYS+t]);
    }
  }
  __syncthreads();
  const float* Lm = a.bufs[bL] + (size_t)(a.offSel[bL] ? a.ctrl->R : 0)*WAYS;
  const float* Hm = a.bufs[bH] + (size_t)(a.offSel[bH] ? a.ctrl->R : 0)*WAYS;
  size_t total = (size_t)n * WAYS;
  double loc = 0.0;
  for (size_t i = (size_t)blockIdx.x*256 + t; i < total; i += (size_t)gridDim.x*256){
    int w = (int)(i % WAYS);
    float lh = Hm[i]*scH[w] - lseH[w];
    float ll = Lm[i]*scL[w] - lseL[w];
    loc += (double)(expf(lh) * (lh - ll));
  }
  __shared__ double sd[256];
  sd[t] = loc; __syncthreads();
  for (int st = 128; st > 0; st >>= 1){
    if (t < st) sd[t] += sd[t + st];
    __syncthreads();
  }
  if (t == 0) atomicAdd(&a.ctrl->klsum[p], sd[0]);
}

// ---- weight sums (both losses batched) -------------------------------------
__global__ __launch_bounds__(256)
void wsum_b(const float* __restrict__ absC, const int* __restrict__ resIdx,
            const int* __restrict__ dctIdx, Ctrl* ctrl){
  int b = blockIdx.y;
  int n = b ? ctrl->Dn : ctrl->R;
  const float* src = b ? (absC + NQ) : absC;
  const int* idx = b ? dctIdx : resIdx;
  double loc = 0.0;
  for (int i = blockIdx.x*256 + threadIdx.x; i < n; i += gridDim.x*256)
    loc += (double)src[idx[i]];
  __shared__ double sd[256];
  sd[threadIdx.x] = loc; __syncthreads();
  for (int st = 128; st > 0; st >>= 1){
    if (threadIdx.x < st) sd[threadIdx.x] += sd[threadIdx.x + st];
    __syncthreads();
  }
  if (threadIdx.x == 0) atomicAdd(&ctrl->wsum[b], sd[0]);
  if (blockIdx.x == 0 && threadIdx.x == 0 && n > 0) ctrl->w0[b] = src[idx[0]];
}

__global__ void final_kernel(const Ctrl* ctrl, const float* tP, const float* tdP,
                             float* out){
  if (threadIdx.x == 0 && blockIdx.x == 0){
    float lossd = ctrl->w0[0] * (float)ctrl->klsum[0] / ((float)ctrl->wsum[0] + 1e-8f);
    float lossr = ctrl->w0[1] * (float)ctrl->klsum[1] / ((float)ctrl->wsum[1] + 1e-8f);
    out[0] = (*tP)  * lossr;
    out[1] = (*tdP) * lossd;
  }
}

extern "C" void kernel_launch(void* const* d_in, const int* in_sizes, int n_in,
                              void* d_out, int out_size, void* d_ws, size_t ws_size,
                              hipStream_t stream)
{
  const float* xs  = (const float*)d_in[0];
  const float* xq  = (const float*)d_in[1];
  const float* dsh = (const float*)d_in[2];
  const float* dq  = (const float*)d_in[3];
  const float* tpP = (const float*)d_in[4];
  const float* tP  = (const float*)d_in[5];
  const float* tdP = (const float*)d_in[6];
  float* out = (float*)d_out;

  char* base = (char*)d_ws;
  Ctrl* ctrl = (Ctrl*)base;
  double*   colSqAll = (double*)(base + 512);                   // 12 x WAYS
  unsigned* maxK     = (unsigned*)(base + 512 + 9600);          // 4 x WAYS
  unsigned* negK     = maxK + 4*WAYS;                           // 4 x WAYS
  double*   sumExp   = (double*)(base + 512 + 9600 + 3200);     // 4 x WAYS
  size_t zone = 512 + 9600 + 3200 + 3200;
  size_t off = (zone + 255) & ~(size_t)255;
  auto alloc = [&](size_t nElem)->void*{ void* p = base + off; off += nElem*4; return p; };
  float* protoX   = (float*)alloc((size_t)WAYS*DIM);
  float* protoD   = (float*)alloc((size_t)WAYS*DIM);
  float* protoRef = (float*)alloc((size_t)4*WAYS*DIM);   // full: 0,1; subset: 0..3
  float* invnX    = (float*)alloc(NQ);
  float* invnD    = (float*)alloc(NQ);
  float* Lx0      = (float*)alloc((size_t)NQ*WAYS);
  float* Ld0      = (float*)alloc((size_t)NQ*WAYS);
  float* absCertF = (float*)alloc((size_t)2*NQ);
  unsigned* keysF = (unsigned*)alloc((size_t)2*NQ);
  int*   pseudoF  = (int*)alloc((size_t)2*NQ);
  float* absCertS = (float*)alloc((size_t)4*NQ);
  unsigned* keysS = (unsigned*)alloc((size_t)4*NQ);
  int*   pseudoS  = (int*)alloc((size_t)4*NQ);
  float* absC     = (float*)alloc((size_t)2*NQ);
  float* relC     = (float*)alloc((size_t)2*NQ);
  int*   selIdx   = (int*)alloc((size_t)4*KSEL);
  float* selVal   = (float*)alloc((size_t)4*KSEL);
  int*   resIdx   = (int*)alloc(NQ);
  int*   dctIdx   = (int*)alloc(NQ);

  // P region: batch-2 split-K slices / pass-2 L (in place) / packed subset L
  float* P = (float*)(base + ((off + 255) & ~(size_t)255));
  size_t offP = (off + 255) & ~(size_t)255;
  int splitkF;
  if (offP + (size_t)2*2*NQ*WAYS*4 <= ws_size) splitkF = 2;
  else if (offP + (size_t)2*1*NQ*WAYS*4 <= ws_size) splitkF = 1;
  else return;
  float* Pb0 = P;
  float* Pb1 = P + (size_t)splitkF*NQ*WAYS;
  float* LxF = Pb0;      // pass-2 L lives in slice 0 of each batch
  float* LdF = Pb1;

  hipMemsetAsync(base, 0, zone, stream);
  proto_kernel<<<2*WAYS, 256, 0, stream>>>(xs, dsh, protoX, protoD);
  invnorm_kernel<<<(2*NQ+3)/4, 256, 0, stream>>>(xq, dq, invnX, invnD);

  dim3 gFull((NQ + BQ - 1)/BQ, (WAYS + BW - 1)/BW, 2*splitkF);
  int sgrid = (NQ + CQ - 1)/CQ;

  // ---------------- full phase, pass 1 ----------------
  GemmArgs g1{};
  g1.feat[0]=xq; g1.feat[1]=dq;
  g1.proto[0]=protoX; g1.proto[1]=protoD;
  g1.nSel[0]=0; g1.nSel[1]=0;
  g1.splitk=splitkF; g1.ctrl=ctrl;
  if (splitkF > 1){
    g1.outP[0]=Pb0; g1.outP[1]=Pb1; g1.applyInvn=0;
  } else {
    g1.outP[0]=Lx0; g1.outP[1]=Ld0; g1.applyInvn=1;
    g1.invn[0]=invnX; g1.invn[1]=invnD;
  }
  gemm_batched<<<gFull,256,0,stream>>>(g1);
  if (splitkF > 1){
    CombArgs c1{}; c1.P=P; c1.invn[0]=invnX; c1.invn[1]=invnD;
    c1.Ltgt[0]=Lx0; c1.Ltgt[1]=Ld0; c1.colSq=colSqAll; c1.splitk=splitkF;
    combine_batched<<<dim3(sgrid,2),256,0,stream>>>(c1);
  } else {
    StatArgs s1{}; s1.Lsrc[0]=Lx0; s1.Lsrc[1]=Ld0;
    s1.nSel[0]=0; s1.nSel[1]=0; s1.colSq=colSqAll; s1.ctrl=ctrl;
    stats_batched<<<dim3(sgrid,2),256,0,stream>>>(s1);
  }
  RS1Args r1{}; r1.Lsrc[0]=Lx0; r1.Lsrc[1]=Ld0;
  r1.nSel[0]=0; r1.nSel[1]=0; r1.colSq=colSqAll; r1.tpP=tpP; r1.ctrl=ctrl;
  r1.absCert=absCertF; r1.keys=keysF; r1.pseudo=pseudoF;
  rowstats1_b<<<dim3((NQ+255)/256,2),256,0,stream>>>(r1);
  SGArgs sg1{}; sg1.keys=keysF; sg1.absCert=absCertF;
  sg1.nSel[0]=0; sg1.nSel[1]=0; sg1.instBase=0;
  sg1.selIdx=selIdx; sg1.selVal=selVal; sg1.ctrl=ctrl;
  selectgather_b<<<2,1024,0,stream>>>(sg1);
  RefArgs rf1{}; rf1.feat[0]=xq; rf1.feat[1]=dq;
  rf1.invn[0]=invnX; rf1.invn[1]=invnD;
  rf1.proto[0]=protoX; rf1.proto[1]=protoD;
  rf1.selIdx=selIdx; rf1.selVal=selVal; rf1.pseudo=pseudoF;
  rf1.protoRef=protoRef; rf1.instBase=0; rf1.ctrl=ctrl;
  refine_b<<<dim3(WAYS,2),256,0,stream>>>(rf1);

  // ---------------- full phase, pass 2 ----------------
  GemmArgs g2 = g1;
  g2.proto[0]=protoRef; g2.proto[1]=protoRef + (size_t)WAYS*DIM;
  if (splitkF == 1){ g2.outP[0]=LxF; g2.outP[1]=LdF; }
  gemm_batched<<<gFull,256,0,stream>>>(g2);
  if (splitkF > 1){
    CombArgs c2{}; c2.P=P; c2.invn[0]=invnX; c2.invn[1]=invnD;
    c2.Ltgt[0]=LxF; c2.Ltgt[1]=LdF; c2.colSq=colSqAll + 2*WAYS; c2.splitk=splitkF;
    combine_batched<<<dim3(sgrid,2),256,0,stream>>>(c2);      // in-place: slice0
  } else {
    StatArgs s2{}; s2.Lsrc[0]=LxF; s2.Lsrc[1]=LdF;
    s2.nSel[0]=0; s2.nSel[1]=0; s2.colSq=colSqAll + 2*WAYS; s2.ctrl=ctrl;
    stats_batched<<<dim3(sgrid,2),256,0,stream>>>(s2);
  }
  RS2Args r2{}; r2.Lsrc[0]=LxF; r2.Lsrc[1]=LdF;
  r2.colSq=colSqAll + 2*WAYS; r2.tpP=tpP; r2.absC=absC; r2.relC=relC;
  rowstats2_b<<<dim3((NQ+255)/256,2),256,0,stream>>>(r2);

  diff_partition<<<1,1024,0,stream>>>(absC, relC, ctrl, resIdx, dctIdx, out);

  // ---------------- subset phase (batch 4: b0 x/res, b1 d/res, b2 d/dct, b3 x/dct)
  // Packed subset L: b0 -> Pb0 rows[0,R), b3 -> Pb0 rows[R,R+Dn);
  //                  b1 -> Pb1 rows[0,R), b2 -> Pb1 rows[R,R+Dn).
  StatArgs ss1{};
  ss1.Lsrc[0]=Lx0; ss1.Lsrc[1]=Ld0; ss1.Lsrc[2]=Ld0; ss1.Lsrc[3]=Lx0;
  ss1.idx[0]=resIdx; ss1.idx[1]=resIdx; ss1.idx[2]=dctIdx; ss1.idx[3]=dctIdx;
  ss1.nSel[0]=1; ss1.nSel[1]=1; ss1.nSel[2]=2; ss1.nSel[3]=2;
  ss1.colSq=colSqAll + 4*WAYS; ss1.ctrl=ctrl;
  stats_batched<<<dim3(sgrid,4),256,0,stream>>>(ss1);
  RS1Args rs{}; rs.Lsrc[0]=Lx0; rs.Lsrc[1]=Ld0; rs.Lsrc[2]=Ld0; rs.Lsrc[3]=Lx0;
  rs.idx[0]=resIdx; rs.idx[1]=resIdx; rs.idx[2]=dctIdx; rs.idx[3]=dctIdx;
  rs.nSel[0]=1; rs.nSel[1]=1; rs.nSel[2]=2; rs.nSel[3]=2;
  rs.colSq=colSqAll + 4*WAYS; rs.tpP=tpP; rs.ctrl=ctrl;
  rs.absCert=absCertS; rs.keys=keysS; rs.pseudo=pseudoS;
  rowstats1_b<<<dim3((NQ+255)/256,4),256,0,stream>>>(rs);
  SGArgs sg2{}; sg2.keys=keysS; sg2.absCert=absCertS;
  sg2.nSel[0]=1; sg2.nSel[1]=1; sg2.nSel[2]=2; sg2.nSel[3]=2; sg2.instBase=2;
  sg2.selIdx=selIdx; sg2.selVal=selVal; sg2.ctrl=ctrl;
  selectgather_b<<<4,1024,0,stream>>>(sg2);
  RefArgs rf2{};
  rf2.feat[0]=xq; rf2.feat[1]=dq; rf2.feat[2]=dq; rf2.feat[3]=xq;
  rf2.idx[0]=resIdx; rf2.idx[1]=resIdx; rf2.idx[2]=dctIdx; rf2.idx[3]=dctIdx;
  rf2.invn[0]=invnX; rf2.invn[1]=invnD; rf2.invn[2]=invnD; rf2.invn[3]=invnX;
  rf2.proto[0]=protoX; rf2.proto[1]=protoD; rf2.proto[2]=protoD; rf2.proto[3]=protoX;
  rf2.selIdx=selIdx; rf2.selVal=selVal; rf2.pseudo=pseudoS;
  rf2.protoRef=protoRef; rf2.instBase=2; rf2.ctrl=ctrl;
  refine_b<<<dim3(WAYS,4),256,0,stream>>>(rf2);
  GemmArgs gs{};
  gs.feat[0]=xq; gs.feat[1]=dq; gs.feat[2]=dq; gs.feat[3]=xq;
  gs.proto[0]=protoRef;
  gs.proto[1]=protoRef + (size_t)WAYS*DIM;
  gs.proto[2]=protoRef + (size_t)2*WAYS*DIM;
  gs.proto[3]=protoRef + (size_t)3*WAYS*DIM;
  gs.outP[0]=Pb0; gs.outP[1]=Pb1; gs.outP[2]=Pb1; gs.outP[3]=Pb0;
  gs.offSel[0]=0; gs.offSel[1]=0; gs.offSel[2]=1; gs.offSel[3]=1;
  gs.idx[0]=resIdx; gs.idx[1]=resIdx; gs.idx[2]=dctIdx; gs.idx[3]=dctIdx;
  gs.invn[0]=invnX; gs.invn[1]=invnD; gs.invn[2]=invnD; gs.invn[3]=invnX;
  gs.nSel[0]=1; gs.nSel[1]=1; gs.nSel[2]=2; gs.nSel[3]=2;
  gs.splitk=1; gs.applyInvn=1; gs.ctrl=ctrl;
  gemm_batched<<<dim3((NQ+BQ-1)/BQ,(WAYS+BW-1)/BW,4),256,0,stream>>>(gs);
  StatArgs ss2{};
  ss2.Lsrc[0]=Pb0; ss2.Lsrc[1]=Pb1; ss2.Lsrc[2]=Pb1; ss2.Lsrc[3]=Pb0;
  ss2.offSel[0]=0; ss2.offSel[1]=0; ss2.offSel[2]=1; ss2.offSel[3]=1;
  ss2.nSel[0]=1; ss2.nSel[1]=1; ss2.nSel[2]=2; ss2.nSel[3]=2;
  ss2.colSq=colSqAll + 8*WAYS; ss2.maxK=maxK; ss2.negK=negK; ss2.ctrl=ctrl;
  stats_batched<<<dim3(sgrid,4),256,0,stream>>>(ss2);
  SEArgs se{};
  se.Lsrc[0]=Pb0; se.Lsrc[1]=Pb1; se.Lsrc[2]=Pb1; se.Lsrc[3]=Pb0;
  se.offSel[0]=0; se.offSel[1]=0; se.offSel[2]=1; se.offSel[3]=1;
  se.nSel[0]=1; se.nSel[1]=1; se.nSel[2]=2; se.nSel[3]=2;
  se.colSq=colSqAll + 8*WAYS; se.maxK=maxK; se.negK=negK;
  se.sumExp=sumExp; se.tpP=tpP; se.ctrl=ctrl;
  sumexp_batched<<<dim3(sgrid,4),256,0,stream>>>(se);
  KLArgs kl{};
  kl.bufs[0]=Pb0; kl.bufs[1]=Pb1; kl.bufs[2]=Pb1; kl.bufs[3]=Pb0;
  kl.offSel[0]=0; kl.offSel[1]=0; kl.offSel[2]=1; kl.offSel[3]=1;
  kl.colSq2=colSqAll + 8*WAYS; kl.maxK=maxK; kl.negK=negK; kl.sumExp=sumExp;
  kl.tpP=tpP; kl.ctrl=ctrl;
  klsum_batched<<<dim3(64,2),256,0,stream>>>(kl);
  wsum_b<<<dim3((NQ+255)/256,2),256,0,stream>>>(absC, resIdx, dctIdx, ctrl);
  final_kernel<<<1,64,0,stream>>>(ctrl, tP, tdP, out);
}

// Round 6
// 950.434 us; speedup vs baseline: 1.1641x; 1.1641x over previous
//
#include <hip/hip_runtime.h>
#include <cstdint>
#include <cstddef>

#define WAYS  100
#define SHOTS 5
#define NQ    10000
#define DIM   2048
#define KSEL  512

#define BQ 128
#define BW 64
#define BK 32
#define PAD 4
#define CQ 64

struct Ctrl {
  double klsum[2];   // [0]=dctl, [1]=resl
  double wsum[2];
  float  w0[2];
  int    R, Dn;
  unsigned int T[8];
  int rem[8];
  int kk[8];
};

__device__ __forceinline__ unsigned int monokey(float f){
  unsigned int b = __float_as_uint(f);
  return (b & 0x80000000u) ? ~b : (b | 0x80000000u);
}
__device__ __forceinline__ float dekey(unsigned int k){
  return (k & 0x80000000u) ? __uint_as_float(k & 0x7FFFFFFFu)
                           : __uint_as_float(~k);
}
__device__ __forceinline__ int decn(int sel, const Ctrl* c){
  return sel == 0 ? NQ : (sel == 1 ? c->R : c->Dn);
}

// ---- prototypes: mean over shots, then row l2-norm -------------------------
__global__ void proto_kernel(const float* __restrict__ xs, const float* __restrict__ dsh,
                             float* __restrict__ protoX, float* __restrict__ protoD){
  int b = blockIdx.x;
  const float* src = (b < WAYS) ? xs : dsh;
  float* dst = (b < WAYS) ? protoX : protoD;
  int w = (b < WAYS) ? b : b - WAYS;
  __shared__ float meanv[DIM];
  __shared__ float red[256];
  float loc = 0.f;
  for (int d = threadIdx.x; d < DIM; d += 256){
    float s = 0.f;
    for (int sh = 0; sh < SHOTS; sh++) s += src[((size_t)w*SHOTS + sh)*DIM + d];
    float m = s / (float)SHOTS;
    meanv[d] = m;
    loc += m*m;
  }
  red[threadIdx.x] = loc; __syncthreads();
  for (int st = 128; st > 0; st >>= 1){
    if (threadIdx.x < st) red[threadIdx.x] += red[threadIdx.x + st];
    __syncthreads();
  }
  float inv = 1.0f / fmaxf(sqrtf(red[0]), 1e-12f);
  for (int d = threadIdx.x; d < DIM; d += 256)
    dst[(size_t)w*DIM + d] = meanv[d] * inv;
}

// ---- per-query inverse L2 norm (4 rows / 256-thread block) -----------------
__global__ __launch_bounds__(256)
void invnorm_kernel(const float* __restrict__ xq, const float* __restrict__ dq,
                    float* __restrict__ invnX, float* __restrict__ invnD){
  int row = blockIdx.x * 4 + (threadIdx.x >> 6);
  if (row >= 2*NQ) return;
  int lane = threadIdx.x & 63;
  const float* src = (row < NQ) ? xq : dq;
  float* dst = (row < NQ) ? invnX : invnD;
  int q = (row < NQ) ? row : row - NQ;
  const float4* r4 = (const float4*)(src + (size_t)q*DIM);
  float s = 0.f;
  for (int i = lane; i < DIM/4; i += 64){
    float4 v = r4[i];
    s += v.x*v.x + v.y*v.y + v.z*v.z + v.w*v.w;
  }
  for (int off = 32; off > 0; off >>= 1) s += __shfl_down(s, off);
  if (lane == 0) dst[q] = 1.0f / fmaxf(sqrtf(s), 1e-12f);
}

// ---- batched split-K GEMM (128x64 tile, 8x4/thread, register prefetch) -----
// R3-proven shape: 32 FMA per 3 ds_read_b128 (1.5 B/MAC), 58% VALU measured.
struct GemmArgs {
  const float* feat[4];
  const float* proto[4];
  const int*   idx[4];
  float*       outP[4];      // + s*NQ*WAYS + rowOff*WAYS
  const float* invn[4];
  int          nSel[4];      // 0->NQ, 1->R, 2->Dn
  int          offSel[4];    // 1 -> row offset ctrl->R in output
  int          splitk;
  int          applyInvn;
  const Ctrl*  ctrl;
};

__global__ __launch_bounds__(256)
void gemm_batched(GemmArgs ga){
  int batch = blockIdx.z / ga.splitk;
  int s     = blockIdx.z % ga.splitk;
  int n = decn(ga.nSel[batch], ga.ctrl);
  int qBase = blockIdx.x * BQ;
  if (qBase >= n) return;
  int wBase = blockIdx.y * BW;
  int kLen  = DIM / ga.splitk;
  int kStart = s * kLen;

  __shared__ float As[BK][BQ+PAD];
  __shared__ float Bs[BK][BW+PAD];

  const float* feat  = ga.feat[batch];
  const float* proto = ga.proto[batch];
  const int*   idxl  = ga.idx[batch];

  int t = threadIdx.x;
  int qr = t & 127;
  int akk0 = t >> 7;                 // 0..1
  int arow = qBase + qr;
  int garow = idxl ? idxl[min(arow, n-1)] : min(arow, n-1);
  const float* pA = feat + (size_t)garow*DIM + kStart;

  int wr = t & 63;
  int wrow = wBase + wr;
  bool bok = (wrow < WAYS);
  const float* pB = proto + (size_t)wrow*DIM + kStart;
  int bkk0 = t >> 6;                 // 0..3

  int tx = t & 15, ty = t >> 4;      // w: tx*4, q: ty*8
  float acc[8][4];
#pragma unroll
  for (int i = 0; i < 8; i++)
#pragma unroll
    for (int j = 0; j < 4; j++) acc[i][j] = 0.f;

  float4 av[4], bv[2];
  const float4 z4 = make_float4(0.f,0.f,0.f,0.f);
#pragma unroll
  for (int i = 0; i < 4; i++) av[i] = *(const float4*)(pA + (akk0 + 2*i)*4);
#pragma unroll
  for (int i = 0; i < 2; i++)
    bv[i] = bok ? *(const float4*)(pB + (bkk0 + 4*i)*4) : z4;

  for (int k0 = 0; k0 < kLen; k0 += BK){
    __syncthreads();
#pragma unroll
    for (int i = 0; i < 4; i++){
      int kk = (akk0 + 2*i)*4;
      As[kk+0][qr]=av[i].x; As[kk+1][qr]=av[i].y; As[kk+2][qr]=av[i].z; As[kk+3][qr]=av[i].w;
    }
#pragma unroll
    for (int i = 0; i < 2; i++){
      int kk = (bkk0 + 4*i)*4;
      Bs[kk+0][wr]=bv[i].x; Bs[kk+1][wr]=bv[i].y; Bs[kk+2][wr]=bv[i].z; Bs[kk+3][wr]=bv[i].w;
    }
    __syncthreads();
    if (k0 + BK < kLen){   // prefetch next tile during compute
#pragma unroll
      for (int i = 0; i < 4; i++) av[i] = *(const float4*)(pA + k0 + BK + (akk0 + 2*i)*4);
#pragma unroll
      for (int i = 0; i < 2; i++)
        bv[i] = bok ? *(const float4*)(pB + k0 + BK + (bkk0 + 4*i)*4) : z4;
    }
#pragma unroll
    for (int kk2 = 0; kk2 < BK; kk2++){
      float4 a0 = *(const float4*)&As[kk2][ty*8];
      float4 a1 = *(const float4*)&As[kk2][ty*8+4];
      float4 b  = *(const float4*)&Bs[kk2][tx*4];
      float a8[8] = {a0.x,a0.y,a0.z,a0.w,a1.x,a1.y,a1.z,a1.w};
#pragma unroll
      for (int i = 0; i < 8; i++){
        acc[i][0]+=a8[i]*b.x; acc[i][1]+=a8[i]*b.y;
        acc[i][2]+=a8[i]*b.z; acc[i][3]+=a8[i]*b.w;
      }
    }
  }
  int rowOff = ga.offSel[batch] ? ga.ctrl->R : 0;
  float* outBase = ga.outP[batch] + ((size_t)s*NQ + (size_t)rowOff)*WAYS;
  int wc = wBase + tx*4;
#pragma unroll
  for (int i = 0; i < 8; i++){
    int q = qBase + ty*8 + i;
    if (q >= n) continue;
    float scr = 1.f;
    if (ga.applyInvn){
      int gq = idxl ? idxl[q] : q;
      scr = ga.invn[batch][gq];
    }
    float* dst = outBase + (size_t)q*WAYS + wc;
    if (wc + 3 < WAYS){
      *(float4*)dst = make_float4(acc[i][0]*scr, acc[i][1]*scr, acc[i][2]*scr, acc[i][3]*scr);
    } else {
#pragma unroll
      for (int j = 0; j < 4; j++) if (wc + j < WAYS) dst[j] = acc[i][j]*scr;
    }
  }
}

// ---- combine K-slices (fixed order), apply invn, colSq; in-place safe ------
struct CombArgs {
  const float* P;            // + b*splitk*NQ*WAYS
  const float* invn[2];
  float* Ltgt[2];            // may alias P slice 0
  double* colSq;             // + b*WAYS
  int splitk;
};
__global__ __launch_bounds__(256)
void combine_batched(CombArgs ca){
  int b = blockIdx.y;
  int qBase = blockIdx.x * CQ;
  int t = threadIdx.x;
  int j = t % 25, r = t / 25;
  const float* Pb = ca.P + (size_t)b*ca.splitk*NQ*WAYS;
  const float* invn = ca.invn[b];
  float* L = ca.Ltgt[b];
  double sq0=0.0, sq1=0.0, sq2=0.0, sq3=0.0;
  if (r < 10){
    for (int i = r; i < CQ; i += 10){
      int q = qBase + i;
      if (q >= NQ) break;
      float sc = invn[q];
      const float* p0 = Pb + (size_t)q*WAYS + 4*j;
      float4 v = *(const float4*)p0;
      for (int s2 = 1; s2 < ca.splitk; s2++){
        float4 u = *(const float4*)(p0 + (size_t)s2*NQ*WAYS);
        v.x += u.x; v.y += u.y; v.z += u.z; v.w += u.w;
      }
      v.x *= sc; v.y *= sc; v.z *= sc; v.w *= sc;
      *(float4*)(L + (size_t)q*WAYS + 4*j) = v;
      sq0 += (double)v.x*(double)v.x;
      sq1 += (double)v.y*(double)v.y;
      sq2 += (double)v.z*(double)v.z;
      sq3 += (double)v.w*(double)v.w;
    }
  }
  __shared__ double red[WAYS][10];
  if (r < 10){
    red[4*j+0][r]=sq0; red[4*j+1][r]=sq1; red[4*j+2][r]=sq2; red[4*j+3][r]=sq3;
  }
  __syncthreads();
  if (t < WAYS){
    double s2 = 0.0;
#pragma unroll
    for (int rr = 0; rr < 10; rr++) s2 += red[t][rr];
    atomicAdd(ca.colSq + (size_t)b*WAYS + t, s2);
  }
}

// ---- subset combine: sum slices + invn, in-place, packed rows --------------
struct CombSubArgs {
  float* buf[2];             // Pb0 (x-features), Pb1 (d-features)
  const float* invn[2];      // invnX, invnD
  const int* resIdx; const int* dctIdx;
  int splitk;
  const Ctrl* ctrl;
};
__global__ __launch_bounds__(256)
void combine_sub(CombSubArgs a){
  int bfi = blockIdx.y;
  int R = a.ctrl->R, Dn = a.ctrl->Dn;
  int n = R + Dn;
  int qBase = blockIdx.x * CQ;
  if (qBase >= n) return;
  int t = threadIdx.x;
  int j = t % 25, r = t / 25;
  if (r >= 10) return;
  float* B = a.buf[bfi];
  const float* invn = a.invn[bfi];
  for (int i = r; i < CQ; i += 10){
    int q = qBase + i;
    if (q >= n) break;
    int gq = (q < R) ? a.resIdx[q] : a.dctIdx[q - R];
    float sc = invn[gq];
    float* p0 = B + (size_t)q*WAYS + 4*j;
    float4 v = *(const float4*)p0;
    for (int s2 = 1; s2 < a.splitk; s2++){
      float4 u = *(const float4*)(p0 + (size_t)s2*NQ*WAYS);
      v.x += u.x; v.y += u.y; v.z += u.z; v.w += u.w;
    }
    v.x *= sc; v.y *= sc; v.z *= sc; v.w *= sc;
    *(float4*)p0 = v;
  }
}

// ---- column stats: colSq + optional per-way min/max (packed-row aware) -----
struct StatArgs {
  const float* Lsrc[4];
  const int*   idx[4];
  int nSel[4];
  int offSel[4];
  double* colSq;          // + b*WAYS
  unsigned* maxK;         // null -> skip minmax
  unsigned* negK;
  const Ctrl* ctrl;
};
__global__ __launch_bounds__(256)
void stats_batched(StatArgs sa){
  int b = blockIdx.y;
  int n = decn(sa.nSel[b], sa.ctrl);
  int qBase = blockIdx.x * CQ;
  if (qBase >= n) return;
  int t = threadIdx.x;
  int j = t % 25, r = t / 25;
  double sq0=0.0, sq1=0.0, sq2=0.0, sq3=0.0;
  float mx0=-3.4e38f,mx1=-3.4e38f,mx2=-3.4e38f,mx3=-3.4e38f;
  float mn0= 3.4e38f,mn1= 3.4e38f,mn2= 3.4e38f,mn3= 3.4e38f;
  if (r < 10){
    const int* idx = sa.idx[b];
    int rowOff = sa.offSel[b] ? sa.ctrl->R : 0;
    const float* L = sa.Lsrc[b] + (size_t)rowOff*WAYS;
    for (int i = r; i < CQ; i += 10){
      int q = qBase + i;
      if (q >= n) break;
      int gq = idx ? idx[q] : q;
      float4 v = *(const float4*)(L + (size_t)gq*WAYS + 4*j);
      sq0 += (double)v.x*(double)v.x; sq1 += (double)v.y*(double)v.y;
      sq2 += (double)v.z*(double)v.z; sq3 += (double)v.w*(double)v.w;
      mx0=fmaxf(mx0,v.x); mx1=fmaxf(mx1,v.y); mx2=fmaxf(mx2,v.z); mx3=fmaxf(mx3,v.w);
      mn0=fminf(mn0,v.x); mn1=fminf(mn1,v.y); mn2=fminf(mn2,v.z); mn3=fminf(mn3,v.w);
    }
  }
  __shared__ double red[WAYS][10];
  if (r < 10){
    red[4*j+0][r]=sq0; red[4*j+1][r]=sq1; red[4*j+2][r]=sq2; red[4*j+3][r]=sq3;
  }
  __syncthreads();
  if (t < WAYS){
    double s2 = 0.0;
#pragma unroll
    for (int rr = 0; rr < 10; rr++) s2 += red[t][rr];
    atomicAdd(sa.colSq + (size_t)b*WAYS + t, s2);
  }
  if (sa.maxK){
    __shared__ float redMx[WAYS][10], redMn[WAYS][10];
    if (r < 10){
      redMx[4*j+0][r]=mx0; redMx[4*j+1][r]=mx1; redMx[4*j+2][r]=mx2; redMx[4*j+3][r]=mx3;
      redMn[4*j+0][r]=mn0; redMn[4*j+1][r]=mn1; redMn[4*j+2][r]=mn2; redMn[4*j+3][r]=mn3;
    }
    __syncthreads();
    if (t < WAYS){
      float mx = -3.4e38f, mn = 3.4e38f;
#pragma unroll
      for (int rr = 0; rr < 10; rr++){ mx = fmaxf(mx, redMx[t][rr]); mn = fminf(mn, redMn[t][rr]); }
      atomicMax(sa.maxK + (size_t)b*WAYS + t, monokey(mx));
      atomicMax(sa.negK + (size_t)b*WAYS + t, monokey(-mn));
    }
  }
}

// ---- per-row max/argmax with lazy scale ------------------------------------
struct RS1Args {
  const float* Lsrc[4];
  const int*   idx[4];
  int nSel[4];
  const double* colSq;   // + b*WAYS
  const float* tpP;
  const Ctrl* ctrl;
  float* absCert; unsigned* keys; int* pseudo;   // + b*NQ
};
__global__ __launch_bounds__(256)
void rowstats1_b(RS1Args a){
  int b = blockIdx.y;
  int n = decn(a.nSel[b], a.ctrl);
  __shared__ float sc[WAYS];
  int t = threadIdx.x;
  if (t < WAYS) sc[t] = (*a.tpP) / ((float)sqrt(a.colSq[(size_t)b*WAYS+t]) + 1e-6f);
  __syncthreads();
  int q = blockIdx.x*256 + t;
  if (q >= n) return;
  int gq = a.idx[b] ? a.idx[b][q] : q;
  const float* row = a.Lsrc[b] + (size_t)gq*WAYS;
  float m = row[0]*sc[0]; int am = 0;
  for (int w = 1; w < WAYS; w++){
    float v = row[w]*sc[w];
    if (v > m){ m = v; am = w; }
  }
  a.absCert[(size_t)b*NQ+q] = m;
  a.pseudo [(size_t)b*NQ+q] = am;
  a.keys   [(size_t)b*NQ+q] = monokey(m);
}

// ---- per-row max + negative entropy (full, batched) ------------------------
struct RS2Args {
  const float* Lsrc[2];
  const double* colSq;   // + b*WAYS
  const float* tpP;
  float* absC; float* relC;   // + b*NQ
};
__global__ __launch_bounds__(256)
void rowstats2_b(RS2Args a){
  int b = blockIdx.y;
  __shared__ float sc[WAYS];
  int t = threadIdx.x;
  if (t < WAYS) sc[t] = (*a.tpP) / ((float)sqrt(a.colSq[(size_t)b*WAYS+t]) + 1e-6f);
  __syncthreads();
  int q = blockIdx.x*256 + t;
  if (q >= NQ) return;
  const float* row = a.Lsrc[b] + (size_t)q*WAYS;
  float m = row[0]*sc[0];
  for (int w = 1; w < WAYS; w++) m = fmaxf(m, row[w]*sc[w]);
  float s = 0.f;
  for (int w = 0; w < WAYS; w++) s += expf(row[w]*sc[w] - m);
  float inv = 1.0f / s, rel = 0.f;
  for (int w = 0; w < WAYS; w++){
    float p = expf(row[w]*sc[w] - m) * inv;
    rel += p * logf(p + 1e-10f);
  }
  a.absC[(size_t)b*NQ+q] = m;
  a.relC[(size_t)b*NQ+q] = rel;
}

// ---- fused radix-select + deterministic stable gather (batched) ------------
struct SGArgs {
  const unsigned* keys; const float* absCert;   // + b*NQ
  int nSel[4]; int instBase;
  int* selIdx; float* selVal;                    // + b*KSEL
  Ctrl* ctrl;
};
__global__ __launch_bounds__(1024)
void selectgather_b(SGArgs a){
  int b = blockIdx.x;
  int inst = a.instBase + b;
  int n = decn(a.nSel[b], a.ctrl);
  int k = n < KSEL ? n : KSEL;
  const unsigned* keys = a.keys + (size_t)b*NQ;
  const float* absCert = a.absCert + (size_t)b*NQ;
  int* selIdx = a.selIdx + b*KSEL;
  float* selVal = a.selVal + b*KSEL;
  __shared__ int hist[256];
  __shared__ unsigned sprefix;
  __shared__ int srem;
  int t = threadIdx.x;
  if (t == 0){ sprefix = 0u; srem = k; }
  __syncthreads();
  int nv4 = n >> 2;
  for (int pass = 0; pass < 4; pass++){
    int shift = 24 - 8*pass;
    if (t < 256) hist[t] = 0;
    __syncthreads();
    unsigned pref = sprefix;
    unsigned mask = (pass == 0) ? 0u : (0xFFFFFFFFu << (shift + 8));
    for (int i = t; i < nv4; i += 1024){
      uint4 kv = ((const uint4*)keys)[i];
      if ((kv.x & mask) == pref) atomicAdd(&hist[(kv.x >> shift) & 255], 1);
      if ((kv.y & mask) == pref) atomicAdd(&hist[(kv.y >> shift) & 255], 1);
      if ((kv.z & mask) == pref) atomicAdd(&hist[(kv.z >> shift) & 255], 1);
      if ((kv.w & mask) == pref) atomicAdd(&hist[(kv.w >> shift) & 255], 1);
    }
    for (int i = 4*nv4 + t; i < n; i += 1024){
      unsigned key = keys[i];
      if ((key & mask) == pref) atomicAdd(&hist[(key >> shift) & 255], 1);
    }
    __syncthreads();
    if (t == 0){
      int acc = 0, rem = srem, sel = 0;
      for (int b2 = 255; b2 >= 0; b2--){
        int h = hist[b2];
        if (acc + h >= rem){ sel = b2; srem = rem - acc; break; }
        acc += h;
      }
      sprefix = pref | ((unsigned)sel << shift);
    }
    __syncthreads();
  }
  unsigned T = sprefix;
  int rem = srem;
  if (t == 0){ a.ctrl->T[inst] = T; a.ctrl->rem[inst] = rem; a.ctrl->kk[inst] = k; }
  int cntGT = k - rem;
  const int CH = 10;
  int q0 = t*CH;
  int fg[CH], fe[CH]; int cg = 0, ce = 0;
  for (int i = 0; i < CH; i++){
    int q = q0 + i; int g = 0, e = 0;
    if (q < n){ unsigned key = keys[q]; g = key > T; e = (key == T); }
    fg[i] = g; fe[i] = e; cg += g; ce += e;
  }
  __shared__ int sG[1024], sE[1024];
  sG[t] = cg; sE[t] = ce; __syncthreads();
  for (int s = 1; s < 1024; s <<= 1){
    int vg = t >= s ? sG[t-s] : 0;
    int ve = t >= s ? sE[t-s] : 0;
    __syncthreads();
    sG[t] += vg; sE[t] += ve;
    __syncthreads();
  }
  int posG = sG[t] - cg, posE = sE[t] - ce;
  for (int i = 0; i < CH; i++){
    int q = q0 + i;
    if (q >= n) break;
    if (fg[i]){ selIdx[posG] = q; selVal[posG] = absCert[q]; posG++; }
    else if (fe[i]){
      if (posE < rem){ selIdx[cntGT+posE] = q; selVal[cntGT+posE] = absCert[q]; }
      posE++;
    }
  }
}

// ---- deterministic proto refine (batched) ----------------------------------
struct RefArgs {
  const float* feat[4]; const int* idx[4];
  const float* invn[4]; const float* proto[4];
  const int* selIdx; const float* selVal;   // + b*KSEL
  const int* pseudo;                        // + b*NQ
  float* protoRef;                          // + b*WAYS*DIM
  int instBase;
  const Ctrl* ctrl;
};
__global__ __launch_bounds__(256)
void refine_b(RefArgs a){
  int b = blockIdx.y;
  int w = blockIdx.x;
  int k = a.ctrl->kk[a.instBase + b];
  const int* selIdx = a.selIdx + b*KSEL;
  const float* selVal = a.selVal + b*KSEL;
  const int* pseudo = a.pseudo + (size_t)b*NQ;
  const int* idxl = a.idx[b];
  __shared__ int   sRow[KSEL];
  __shared__ float sCoef[KSEL];
  int t = threadIdx.x;
  for (int j = t; j < k; j += 256){
    int srow = selIdx[j];
    int grow = idxl ? idxl[srow] : srow;
    sRow[j]  = (pseudo[srow] == w) ? grow : -1;
    sCoef[j] = selVal[j] * a.invn[b][grow] / (float)k;
  }
  __syncthreads();
  float4 acc0 = make_float4(0.f,0.f,0.f,0.f);
  float4 acc1 = make_float4(0.f,0.f,0.f,0.f);
  int d0 = t*4, d1 = t*4 + 1024;
  const float* feat = a.feat[b];
  for (int j = 0; j < k; j++){
    int grow = sRow[j];
    if (grow < 0) continue;
    float c = sCoef[j];
    const float* fr = feat + (size_t)grow*DIM;
    float4 f0 = *(const float4*)(fr + d0);
    float4 f1 = *(const float4*)(fr + d1);
    acc0.x += c*f0.x; acc0.y += c*f0.y; acc0.z += c*f0.z; acc0.w += c*f0.w;
    acc1.x += c*f1.x; acc1.y += c*f1.y; acc1.z += c*f1.z; acc1.w += c*f1.w;
  }
  const float* pw = a.proto[b] + (size_t)w*DIM;
  float* pr = a.protoRef + ((size_t)b*WAYS + w)*DIM;
  float4 p0 = *(const float4*)(pw + d0);
  float4 p1 = *(const float4*)(pw + d1);
  *(float4*)(pr + d0) = make_float4(p0.x+acc0.x, p0.y+acc0.y, p0.z+acc0.z, p0.w+acc0.w);
  *(float4*)(pr + d1) = make_float4(p1.x+acc1.x, p1.y+acc1.y, p1.z+acc1.z, p1.w+acc1.w);
}

// ---- diff sign partition + index + w_r/w_f outputs -------------------------
__global__ __launch_bounds__(1024)
void diff_partition(const float* __restrict__ absC, const float* __restrict__ relC,
                    Ctrl* ctrl, int* __restrict__ resIdx, int* __restrict__ dctIdx,
                    float* __restrict__ out){
  const float* absCx = absC;        const float* absCd = absC + NQ;
  const float* relCx = relC;        const float* relCd = relC + NQ;
  const int CH = 10;
  int t = threadIdx.x, q0 = t*CH;
  int fr[CH], fd[CH]; int cr = 0, cd = 0;
  for (int i = 0; i < CH; i++){
    int q = q0 + i; int r = 0, dn = 0;
    if (q < NQ){
      float dv = absCx[q] - absCd[q] + relCx[q] - relCd[q];
      r = dv > 0.f; dn = dv < 0.f;
    }
    fr[i] = r; fd[i] = dn; cr += r; cd += dn;
  }
  __shared__ int sR[1024], sD[1024];
  sR[t] = cr; sD[t] = cd; __syncthreads();
  for (int s = 1; s < 1024; s <<= 1){
    int vr = t >= s ? sR[t-s] : 0;
    int vd = t >= s ? sD[t-s] : 0;
    __syncthreads();
    sR[t] += vr; sD[t] += vd;
    __syncthreads();
  }
  int R = sR[1023], Dn = sD[1023];
  int posR = sR[t] - cr, posD = sD[t] - cd;
  if (t == 0){ ctrl->R = R; ctrl->Dn = Dn; }
  for (int i = 0; i < CH; i++){
    int q = q0 + i;
    if (q >= NQ) break;
    if (fr[i]){ resIdx[posR] = q; out[2+posR] = (float)q; posR++; }
    if (fd[i]){ dctIdx[posD] = q; out[2+R+posD] = (float)q; posD++; }
  }
  for (int q = t; q < NQ; q += 1024){
    float a = absCx[q], b = absCd[q];
    float den = fmaxf(a + b, 1e-8f);
    out[2+R+Dn+q]      = a / den;
    out[2+R+Dn+NQ+q]   = b / den;
  }
}

// ---- per-way sum of exp(v*sc - m) (row-major, batched, packed rows) --------
struct SEArgs {
  const float* Lsrc[4];
  int nSel[4];
  int offSel[4];
  const double* colSq;       // + b*WAYS
  const unsigned* maxK; const unsigned* negK;
  double* sumExp;            // + b*WAYS
  const float* tpP;
  const Ctrl* ctrl;
};
__global__ __launch_bounds__(256)
void sumexp_batched(SEArgs a){
  int b = blockIdx.y;
  int n = decn(a.nSel[b], a.ctrl);
  int t = threadIdx.x;
  __shared__ float sc[WAYS], mv[WAYS];
  if (t < WAYS){
    float s = (*a.tpP) / ((float)sqrt(a.colSq[(size_t)b*WAYS+t]) + 1e-6f);
    float mxv = dekey(a.maxK[(size_t)b*WAYS+t]);
    float mnv = -dekey(a.negK[(size_t)b*WAYS+t]);
    sc[t] = s; mv[t] = (s >= 0.f) ? s*mxv : s*mnv;
  }
  __syncthreads();
  int qBase = blockIdx.x * CQ;
  if (qBase >= n) return;
  int j = t % 25, r = t / 25;
  double e0=0.0,e1=0.0,e2=0.0,e3=0.0;
  if (r < 10){
    int rowOff = a.offSel[b] ? a.ctrl->R : 0;
    const float* L = a.Lsrc[b] + (size_t)rowOff*WAYS;
    float s0=sc[4*j+0], s1=sc[4*j+1], s2=sc[4*j+2], s3=sc[4*j+3];
    float m0=mv[4*j+0], m1=mv[4*j+1], m2=mv[4*j+2], m3=mv[4*j+3];
    for (int i = r; i < CQ; i += 10){
      int q = qBase + i;
      if (q >= n) break;
      float4 v = *(const float4*)(L + (size_t)q*WAYS + 4*j);
      e0 += (double)expf(v.x*s0 - m0);
      e1 += (double)expf(v.y*s1 - m1);
      e2 += (double)expf(v.z*s2 - m2);
      e3 += (double)expf(v.w*s3 - m3);
    }
  }
  __shared__ double red[WAYS][10];
  if (r < 10){
    red[4*j+0][r]=e0; red[4*j+1][r]=e1; red[4*j+2][r]=e2; red[4*j+3][r]=e3;
  }
  __syncthreads();
  if (t < WAYS){
    double s2 = 0.0;
#pragma unroll
    for (int rr = 0; rr < 10; rr++) s2 += red[t][rr];
    atomicAdd(a.sumExp + (size_t)b*WAYS + t, s2);
  }
}

// ---- KL sum (two pairs batched, packed rows) --------------------------------
struct KLArgs {
  const float* bufs[4];
  int offSel[4];
  const double* colSq2;      // + b*WAYS
  const unsigned* maxK; const unsigned* negK; const double* sumExp;
  const float* tpP;
  Ctrl* ctrl;
};
__global__ __launch_bounds__(256)
void klsum_batched(KLArgs a){
  int p = blockIdx.y;
  int bL = p ? 3 : 1, bH = p ? 2 : 0;
  int n = p ? a.ctrl->Dn : a.ctrl->R;
  __shared__ float scL[WAYS], lseL[WAYS], scH[WAYS], lseH[WAYS];
  int t = threadIdx.x;
  if (t < WAYS){
    float tp = *a.tpP;
    {
      float s = tp / ((float)sqrt(a.colSq2[(size_t)bL*WAYS+t]) + 1e-6f);
      float mxv = dekey(a.maxK[(size_t)bL*WAYS+t]);
      float mnv = -dekey(a.negK[(size_t)bL*WAYS+t]);
      float m = (s >= 0.f) ? s*mxv : s*mnv;
      scL[t] = s; lseL[t] = m + (float)log(a.sumExp[(size_t)bL*WAYS+t]);
    }
    {
      float s = tp / ((float)sqrt(a.colSq2[(size_t)bH*WAYS+t]) + 1e-6f);
      float mxv = dekey(a.maxK[(size_t)bH*WAYS+t]);
      float mnv = -dekey(a.negK[(size_t)bH*WAYS+t]);
      float m = (s >= 0.f) ? s*mxv : s*mnv;
      scH[t] = s; lseH[t] = m + (float)log(a.sumExp[(size_t)bH*WAYS+t]);
    }
  }
  __syncthreads();
  const float* Lm = a.bufs[bL] + (size_t)(a.offSel[bL] ? a.ctrl->R : 0)*WAYS;
  const float* Hm = a.bufs[bH] + (size_t)(a.offSel[bH] ? a.ctrl->R : 0)*WAYS;
  size_t total = (size_t)n * WAYS;
  double loc = 0.0;
  for (size_t i = (size_t)blockIdx.x*256 + t; i < total; i += (size_t)gridDim.x*256){
    int w = (int)(i % WAYS);
    float lh = Hm[i]*scH[w] - lseH[w];
    float ll = Lm[i]*scL[w] - lseL[w];
    loc += (double)(expf(lh) * (lh - ll));
  }
  __shared__ double sd[256];
  sd[t] = loc; __syncthreads();
  for (int st = 128; st > 0; st >>= 1){
    if (t < st) sd[t] += sd[t + st];
    __syncthreads();
  }
  if (t == 0) atomicAdd(&a.ctrl->klsum[p], sd[0]);
}

// ---- weight sums (both losses batched) -------------------------------------
__global__ __launch_bounds__(256)
void wsum_b(const float* __restrict__ absC, const int* __restrict__ resIdx,
            const int* __restrict__ dctIdx, Ctrl* ctrl){
  int b = blockIdx.y;
  int n = b ? ctrl->Dn : ctrl->R;
  const float* src = b ? (absC + NQ) : absC;
  const int* idx = b ? dctIdx : resIdx;
  double loc = 0.0;
  for (int i = blockIdx.x*256 + threadIdx.x; i < n; i += gridDim.x*256)
    loc += (double)src[idx[i]];
  __shared__ double sd[256];
  sd[threadIdx.x] = loc; __syncthreads();
  for (int st = 128; st > 0; st >>= 1){
    if (threadIdx.x < st) sd[threadIdx.x] += sd[threadIdx.x + st];
    __syncthreads();
  }
  if (threadIdx.x == 0) atomicAdd(&ctrl->wsum[b], sd[0]);
  if (blockIdx.x == 0 && threadIdx.x == 0 && n > 0) ctrl->w0[b] = src[idx[0]];
}

__global__ void final_kernel(const Ctrl* ctrl, const float* tP, const float* tdP,
                             float* out){
  if (threadIdx.x == 0 && blockIdx.x == 0){
    float lossd = ctrl->w0[0] * (float)ctrl->klsum[0] / ((float)ctrl->wsum[0] + 1e-8f);
    float lossr = ctrl->w0[1] * (float)ctrl->klsum[1] / ((float)ctrl->wsum[1] + 1e-8f);
    out[0] = (*tP)  * lossr;
    out[1] = (*tdP) * lossd;
  }
}

extern "C" void kernel_launch(void* const* d_in, const int* in_sizes, int n_in,
                              void* d_out, int out_size, void* d_ws, size_t ws_size,
                              hipStream_t stream)
{
  const float* xs  = (const float*)d_in[0];
  const float* xq  = (const float*)d_in[1];
  const float* dsh = (const float*)d_in[2];
  const float* dq  = (const float*)d_in[3];
  const float* tpP = (const float*)d_in[4];
  const float* tP  = (const float*)d_in[5];
  const float* tdP = (const float*)d_in[6];
  float* out = (float*)d_out;

  char* base = (char*)d_ws;
  Ctrl* ctrl = (Ctrl*)base;
  double*   colSqAll = (double*)(base + 512);                   // 12 x WAYS
  unsigned* maxK     = (unsigned*)(base + 512 + 9600);          // 4 x WAYS
  unsigned* negK     = maxK + 4*WAYS;                           // 4 x WAYS
  double*   sumExp   = (double*)(base + 512 + 9600 + 3200);     // 4 x WAYS
  size_t zone = 512 + 9600 + 3200 + 3200;
  size_t off = (zone + 255) & ~(size_t)255;
  auto alloc = [&](size_t nElem)->void*{ void* p = base + off; off += nElem*4; return p; };
  float* protoX   = (float*)alloc((size_t)WAYS*DIM);
  float* protoD   = (float*)alloc((size_t)WAYS*DIM);
  float* protoRef = (float*)alloc((size_t)4*WAYS*DIM);   // full: 0,1; subset: 0..3
  float* invnX    = (float*)alloc(NQ);
  float* invnD    = (float*)alloc(NQ);
  float* Lx0      = (float*)alloc((size_t)NQ*WAYS);
  float* Ld0      = (float*)alloc((size_t)NQ*WAYS);
  float* absCertF = (float*)alloc((size_t)2*NQ);
  unsigned* keysF = (unsigned*)alloc((size_t)2*NQ);
  int*   pseudoF  = (int*)alloc((size_t)2*NQ);
  float* absCertS = (float*)alloc((size_t)4*NQ);
  unsigned* keysS = (unsigned*)alloc((size_t)4*NQ);
  int*   pseudoS  = (int*)alloc((size_t)4*NQ);
  float* absC     = (float*)alloc((size_t)2*NQ);
  float* relC     = (float*)alloc((size_t)2*NQ);
  int*   selIdx   = (int*)alloc((size_t)4*KSEL);
  float* selVal   = (float*)alloc((size_t)4*KSEL);
  int*   resIdx   = (int*)alloc(NQ);
  int*   dctIdx   = (int*)alloc(NQ);

  size_t offP = (off + 255) & ~(size_t)255;
  float* P = (float*)(base + offP);
  int splitkF;
  if      (offP + (size_t)2*4*NQ*WAYS*4 <= ws_size) splitkF = 4;
  else if (offP + (size_t)2*2*NQ*WAYS*4 <= ws_size) splitkF = 2;
  else if (offP + (size_t)2*1*NQ*WAYS*4 <= ws_size) splitkF = 1;
  else return;
  float* Pb0 = P;
  float* Pb1 = P + (size_t)splitkF*NQ*WAYS;
  float* LxF = Pb0;      // pass-2 L lives in slice 0 of each batch
  float* LdF = Pb1;

  hipMemsetAsync(base, 0, zone, stream);
  proto_kernel<<<2*WAYS, 256, 0, stream>>>(xs, dsh, protoX, protoD);
  invnorm_kernel<<<(2*NQ+3)/4, 256, 0, stream>>>(xq, dq, invnX, invnD);

  dim3 gFull((NQ + BQ - 1)/BQ, (WAYS + BW - 1)/BW, 2*splitkF);
  int sgrid = (NQ + CQ - 1)/CQ;

  // ---------------- full phase, pass 1 ----------------
  GemmArgs g1{};
  g1.feat[0]=xq; g1.feat[1]=dq;
  g1.proto[0]=protoX; g1.proto[1]=protoD;
  g1.nSel[0]=0; g1.nSel[1]=0;
  g1.splitk=splitkF; g1.ctrl=ctrl;
  if (splitkF > 1){
    g1.outP[0]=Pb0; g1.outP[1]=Pb1; g1.applyInvn=0;
  } else {
    g1.outP[0]=Lx0; g1.outP[1]=Ld0; g1.applyInvn=1;
    g1.invn[0]=invnX; g1.invn[1]=invnD;
  }
  gemm_batched<<<gFull,256,0,stream>>>(g1);
  if (splitkF > 1){
    CombArgs c1{}; c1.P=P; c1.invn[0]=invnX; c1.invn[1]=invnD;
    c1.Ltgt[0]=Lx0; c1.Ltgt[1]=Ld0; c1.colSq=colSqAll; c1.splitk=splitkF;
    combine_batched<<<dim3(sgrid,2),256,0,stream>>>(c1);
  } else {
    StatArgs s1{}; s1.Lsrc[0]=Lx0; s1.Lsrc[1]=Ld0;
    s1.nSel[0]=0; s1.nSel[1]=0; s1.colSq=colSqAll; s1.ctrl=ctrl;
    stats_batched<<<dim3(sgrid,2),256,0,stream>>>(s1);
  }
  RS1Args r1{}; r1.Lsrc[0]=Lx0; r1.Lsrc[1]=Ld0;
  r1.nSel[0]=0; r1.nSel[1]=0; r1.colSq=colSqAll; r1.tpP=tpP; r1.ctrl=ctrl;
  r1.absCert=absCertF; r1.keys=keysF; r1.pseudo=pseudoF;
  rowstats1_b<<<dim3((NQ+255)/256,2),256,0,stream>>>(r1);
  SGArgs sg1{}; sg1.keys=keysF; sg1.absCert=absCertF;
  sg1.nSel[0]=0; sg1.nSel[1]=0; sg1.instBase=0;
  sg1.selIdx=selIdx; sg1.selVal=selVal; sg1.ctrl=ctrl;
  selectgather_b<<<2,1024,0,stream>>>(sg1);
  RefArgs rf1{}; rf1.feat[0]=xq; rf1.feat[1]=dq;
  rf1.invn[0]=invnX; rf1.invn[1]=invnD;
  rf1.proto[0]=protoX; rf1.proto[1]=protoD;
  rf1.selIdx=selIdx; rf1.selVal=selVal; rf1.pseudo=pseudoF;
  rf1.protoRef=protoRef; rf1.instBase=0; rf1.ctrl=ctrl;
  refine_b<<<dim3(WAYS,2),256,0,stream>>>(rf1);

  // ---------------- full phase, pass 2 ----------------
  GemmArgs g2 = g1;
  g2.proto[0]=protoRef; g2.proto[1]=protoRef + (size_t)WAYS*DIM;
  if (splitkF == 1){ g2.outP[0]=LxF; g2.outP[1]=LdF; }
  gemm_batched<<<gFull,256,0,stream>>>(g2);
  if (splitkF > 1){
    CombArgs c2{}; c2.P=P; c2.invn[0]=invnX; c2.invn[1]=invnD;
    c2.Ltgt[0]=LxF; c2.Ltgt[1]=LdF; c2.colSq=colSqAll + 2*WAYS; c2.splitk=splitkF;
    combine_batched<<<dim3(sgrid,2),256,0,stream>>>(c2);      // in-place: slice0
  } else {
    StatArgs s2{}; s2.Lsrc[0]=LxF; s2.Lsrc[1]=LdF;
    s2.nSel[0]=0; s2.nSel[1]=0; s2.colSq=colSqAll + 2*WAYS; s2.ctrl=ctrl;
    stats_batched<<<dim3(sgrid,2),256,0,stream>>>(s2);
  }
  RS2Args r2{}; r2.Lsrc[0]=LxF; r2.Lsrc[1]=LdF;
  r2.colSq=colSqAll + 2*WAYS; r2.tpP=tpP; r2.absC=absC; r2.relC=relC;
  rowstats2_b<<<dim3((NQ+255)/256,2),256,0,stream>>>(r2);

  diff_partition<<<1,1024,0,stream>>>(absC, relC, ctrl, resIdx, dctIdx, out);

  // ---------------- subset phase (b0 x/res, b1 d/res, b2 d/dct, b3 x/dct) ---
  // Packed subset L: b0 -> Pb0 rows[0,R), b3 -> Pb0 rows[R,R+Dn);
  //                  b1 -> Pb1 rows[0,R), b2 -> Pb1 rows[R,R+Dn).
  StatArgs ss1{};
  ss1.Lsrc[0]=Lx0; ss1.Lsrc[1]=Ld0; ss1.Lsrc[2]=Ld0; ss1.Lsrc[3]=Lx0;
  ss1.idx[0]=resIdx; ss1.idx[1]=resIdx; ss1.idx[2]=dctIdx; ss1.idx[3]=dctIdx;
  ss1.nSel[0]=1; ss1.nSel[1]=1; ss1.nSel[2]=2; ss1.nSel[3]=2;
  ss1.colSq=colSqAll + 4*WAYS; ss1.ctrl=ctrl;
  stats_batched<<<dim3(sgrid,4),256,0,stream>>>(ss1);
  RS1Args rs{}; rs.Lsrc[0]=Lx0; rs.Lsrc[1]=Ld0; rs.Lsrc[2]=Ld0; rs.Lsrc[3]=Lx0;
  rs.idx[0]=resIdx; rs.idx[1]=resIdx; rs.idx[2]=dctIdx; rs.idx[3]=dctIdx;
  rs.nSel[0]=1; rs.nSel[1]=1; rs.nSel[2]=2; rs.nSel[3]=2;
  rs.colSq=colSqAll + 4*WAYS; rs.tpP=tpP; rs.ctrl=ctrl;
  rs.absCert=absCertS; rs.keys=keysS; rs.pseudo=pseudoS;
  rowstats1_b<<<dim3((NQ+255)/256,4),256,0,stream>>>(rs);
  SGArgs sg2{}; sg2.keys=keysS; sg2.absCert=absCertS;
  sg2.nSel[0]=1; sg2.nSel[1]=1; sg2.nSel[2]=2; sg2.nSel[3]=2; sg2.instBase=2;
  sg2.selIdx=selIdx; sg2.selVal=selVal; sg2.ctrl=ctrl;
  selectgather_b<<<4,1024,0,stream>>>(sg2);
  RefArgs rf2{};
  rf2.feat[0]=xq; rf2.feat[1]=dq; rf2.feat[2]=dq; rf2.feat[3]=xq;
  rf2.idx[0]=resIdx; rf2.idx[1]=resIdx; rf2.idx[2]=dctIdx; rf2.idx[3]=dctIdx;
  rf2.invn[0]=invnX; rf2.invn[1]=invnD; rf2.invn[2]=invnD; rf2.invn[3]=invnX;
  rf2.proto[0]=protoX; rf2.proto[1]=protoD; rf2.proto[2]=protoD; rf2.proto[3]=protoX;
  rf2.selIdx=selIdx; rf2.selVal=selVal; rf2.pseudo=pseudoS;
  rf2.protoRef=protoRef; rf2.instBase=2; rf2.ctrl=ctrl;
  refine_b<<<dim3(WAYS,4),256,0,stream>>>(rf2);

  int splitkS = splitkF;
  GemmArgs gs{};
  gs.feat[0]=xq; gs.feat[1]=dq; gs.feat[2]=dq; gs.feat[3]=xq;
  gs.proto[0]=protoRef;
  gs.proto[1]=protoRef + (size_t)WAYS*DIM;
  gs.proto[2]=protoRef + (size_t)2*WAYS*DIM;
  gs.proto[3]=protoRef + (size_t)3*WAYS*DIM;
  gs.outP[0]=Pb0; gs.outP[1]=Pb1; gs.outP[2]=Pb1; gs.outP[3]=Pb0;
  gs.offSel[0]=0; gs.offSel[1]=0; gs.offSel[2]=1; gs.offSel[3]=1;
  gs.idx[0]=resIdx; gs.idx[1]=resIdx; gs.idx[2]=dctIdx; gs.idx[3]=dctIdx;
  gs.invn[0]=invnX; gs.invn[1]=invnD; gs.invn[2]=invnD; gs.invn[3]=invnX;
  gs.nSel[0]=1; gs.nSel[1]=1; gs.nSel[2]=2; gs.nSel[3]=2;
  gs.splitk=splitkS; gs.applyInvn=(splitkS == 1); gs.ctrl=ctrl;
  gemm_batched<<<dim3((NQ+BQ-1)/BQ,(WAYS+BW-1)/BW,4*splitkS),256,0,stream>>>(gs);
  if (splitkS > 1){
    CombSubArgs cs{};
    cs.buf[0]=Pb0; cs.buf[1]=Pb1;
    cs.invn[0]=invnX; cs.invn[1]=invnD;
    cs.resIdx=resIdx; cs.dctIdx=dctIdx;
    cs.splitk=splitkS; cs.ctrl=ctrl;
    combine_sub<<<dim3(sgrid,2),256,0,stream>>>(cs);
  }
  StatArgs ss2{};
  ss2.Lsrc[0]=Pb0; ss2.Lsrc[1]=Pb1; ss2.Lsrc[2]=Pb1; ss2.Lsrc[3]=Pb0;
  ss2.offSel[0]=0; ss2.offSel[1]=0; ss2.offSel[2]=1; ss2.offSel[3]=1;
  ss2.nSel[0]=1; ss2.nSel[1]=1; ss2.nSel[2]=2; ss2.nSel[3]=2;
  ss2.colSq=colSqAll + 8*WAYS; ss2.maxK=maxK; ss2.negK=negK; ss2.ctrl=ctrl;
  stats_batched<<<dim3(sgrid,4),256,0,stream>>>(ss2);
  SEArgs se{};
  se.Lsrc[0]=Pb0; se.Lsrc[1]=Pb1; se.Lsrc[2]=Pb1; se.Lsrc[3]=Pb0;
  se.offSel[0]=0; se.offSel[1]=0; se.offSel[2]=1; se.offSel[3]=1;
  se.nSel[0]=1; se.nSel[1]=1; se.nSel[2]=2; se.nSel[3]=2;
  se.colSq=colSqAll + 8*WAYS; se.maxK=maxK; se.negK=negK;
  se.sumExp=sumExp; se.tpP=tpP; se.ctrl=ctrl;
  sumexp_batched<<<dim3(sgrid,4),256,0,stream>>>(se);
  KLArgs kl{};
  kl.bufs[0]=Pb0; kl.bufs[1]=Pb1; kl.bufs[2]=Pb1; kl.bufs[3]=Pb0;
  kl.offSel[0]=0; kl.offSel[1]=0; kl.offSel[2]=1; kl.offSel[3]=1;
  kl.colSq2=colSqAll + 8*WAYS; kl.maxK=maxK; kl.negK=negK; kl.sumExp=sumExp;
  kl.tpP=tpP; kl.ctrl=ctrl;
  klsum_batched<<<dim3(64,2),256,0,stream>>>(kl);
  wsum_b<<<dim3((NQ+255)/256,2),256,0,stream>>>(absC, resIdx, dctIdx, ctrl);
  final_kernel<<<1,64,0,stream>>>(ctrl, tP, tdP, out);
}